// Round 9
// baseline (5652.343 us; speedup 1.0000x reference)
//
#include <hip/hip_runtime.h>

// CUBA Spiking CNN, B=32, T=100.
// R9: 4-stage cross-CU pipeline (128 blocks):
//   A  [0,32):   conv1 + conv2(MFMA f16 hi/lo split) + pool -> nibble-packed
//                pooled counts (144 dw) + flagA
//   B  [32,64):  conv3 oc 0..127   (sparse compacted stream) -> 4 dw spike bits
//   B' [64,96):  conv3 oc 128..255 -> 4 dw spike bits + flagB2
//   C  [96,128): tc + rec + fc1 + fc2/acc, bitmask-driven sparse streams,
//                tc-stream || rec-stream in one phase (rec uses s5_prev).
// Fallback to R7 monolithic kernel if ws_size too small.

#define VTH 0.5f

// d_ws dword offsets
#define W2P_OFF  0
#define W3P_OFF  73728
#define TCP_OFF  368640
#define RECP_OFF 565248
#define FC1P_OFF 630784
#define WS_FLOATS 663552
#define P2G_OFF   WS_FLOATS                    // 144 dw per (b,t), nibble counts
#define SP3_OFF   (P2G_OFF + 32 * 100 * 144)   // 8 dw per (b,t), conv3 spike bits
#define FLA_OFF   (SP3_OFF + 32 * 100 * 8)
#define FLB_OFF   (FLA_OFF + 3200)
#define FLB2_OFF  (FLB_OFF + 3200)
#define WS_DW_END (FLB2_OFF + 3200)
#define WS_NEED_BYTES ((size_t)WS_DW_END * 4)

typedef __attribute__((ext_vector_type(8))) _Float16 half8v;
typedef __attribute__((ext_vector_type(4))) float f32x4;

__device__ inline unsigned short f2h_bits(float x) {
  union { _Float16 h; unsigned short u; } c; c.h = (_Float16)x; return c.u;
}
__device__ inline float h2f(unsigned short u) {
  union { unsigned short u; _Float16 h; } c; c.u = u; return (float)c.h;
}

__global__ __launch_bounds__(256) void prep_weights(
    const float* __restrict__ w2, const float* __restrict__ w3,
    const float* __restrict__ tcw, const float* __restrict__ recw,
    const float* __restrict__ fc1w, float* __restrict__ ws)
{
  int idx = blockIdx.x * 256 + threadIdx.x;
  if (idx < W3P_OFF) {
    int frag = idx >> 8, r = idx & 255;
    int lane = r >> 2, dw = r & 3;
    int half = frag & 1, nt = (frag >> 1) & 7, kt = frag >> 4;
    unsigned out = 0;
    #pragma unroll
    for (int j2 = 0; j2 < 2; ++j2) {
      int j = dw * 2 + j2;
      int oc = nt * 16 + (lane & 15);
      int k = kt * 32 + ((lane >> 4) << 3) + j;
      int c = k & 63, tap = k >> 6;
      float w = w2[(oc * 64 + c) * 9 + tap];
      unsigned short hb = f2h_bits(w);
      unsigned short bits = half ? f2h_bits((w - h2f(hb)) * 4096.f) : hb;
      out |= ((unsigned)bits) << (16 * j2);
    }
    ((unsigned*)ws)[idx] = out;
  } else if (idx < TCP_OFF) {
    int i = idx - W3P_OFF;
    int r = i & 3, ocq = (i >> 2) & 63, k = i >> 8;
    int oc = ocq * 4 + r, c = k & 127, pos9 = k >> 7;
    ws[idx] = w3[(oc * 128 + c) * 9 + pos9];
  } else if (idx < RECP_OFF) {
    int i = idx - TCP_OFF;
    int r = i & 3, dq = (i >> 2) & 63, k = i >> 8;
    int d = dq * 4 + r, c = k & 255, kk = k >> 8;
    ws[idx] = tcw[(kk * 256 + d) * 256 + c];
  } else if (idx < FC1P_OFF) {
    int i = idx - RECP_OFF;
    int r = i & 3, dq = (i >> 2) & 63, c = i >> 8;
    ws[idx] = recw[(dq * 4 + r) * 256 + c];
  } else if (idx < WS_FLOATS) {
    int i = idx - FC1P_OFF;
    int r = i & 3, dq = (i >> 2) & 31, c = i >> 7;
    ws[idx] = fc1w[(dq * 4 + r) * 256 + c];
  }
}

__global__ __launch_bounds__(256) void zero_flags(float* __restrict__ ws) {
  int i = blockIdx.x * 256 + threadIdx.x;
  if (i < (WS_DW_END - FLA_OFF)) ((unsigned*)ws)[FLA_OFF + i] = 0u;
}

// ---------------------------------------------------------------------------
// 4-stage pipelined kernel, 128 blocks x 1024 threads
// ---------------------------------------------------------------------------
__global__ __launch_bounds__(1024, 4) void snn_pipe(
    const float* __restrict__ input, const float* __restrict__ w1g,
    const float* __restrict__ b1g, const float* __restrict__ b2g,
    const float* __restrict__ b3g, const float* __restrict__ tcbg,
    const float* __restrict__ recbg, const float* __restrict__ fc1bg,
    const float* __restrict__ fc2wg, const float* __restrict__ tswg,
    const float* __restrict__ maskg,
    const float* __restrict__ c1sg, const float* __restrict__ c2sg,
    const float* __restrict__ c3sg, const float* __restrict__ tcsg,
    const float* __restrict__ rsg, const float* __restrict__ fsg,
    float* __restrict__ ws, float* __restrict__ out)
{
  const int tid = threadIdx.x;
  const int wv  = tid >> 6;
  const int ln  = tid & 63;
  unsigned* p2g   = (unsigned*)ws + P2G_OFF;
  unsigned* sp3g  = (unsigned*)ws + SP3_OFF;
  unsigned* flagA = (unsigned*)ws + FLA_OFF;
  unsigned* flagB = (unsigned*)ws + FLB_OFF;
  unsigned* flagB2= (unsigned*)ws + FLB2_OFF;

  const int role = blockIdx.x >> 5;       // 0=A, 1=B(lo), 2=B(hi), 3=C
  const int b    = blockIdx.x & 31;

  if (role == 0) {
    // ======================= STAGE A: conv1 + conv2 + pool ==================
    const half8v* w2h = (const half8v*)ws;
    __shared__ float xt[100];
    __shared__ __align__(16) unsigned short s1b[84 * 64];
    __shared__ unsigned short s2b[36 * 128];
    __shared__ float b2L[128];
    __shared__ unsigned char p2nb[1152];

    const int co = ln, pos0 = wv;
    float w1r[9];
    #pragma unroll
    for (int k = 0; k < 9; ++k) w1r[k] = w1g[co * 9 + k];
    const float b1r = b1g[co];
    float sp1[4], cur1[4], vol1[4];
    #pragma unroll
    for (int j = 0; j < 4; ++j) {
      int pos = pos0 + 16 * j;
      sp1[j]  = c1sg[((0 * 32 + b) * 64 + co) * 64 + pos];
      cur1[j] = c1sg[((1 * 32 + b) * 64 + co) * 64 + pos];
      vol1[j] = c1sg[((2 * 32 + b) * 64 + co) * 64 + pos];
    }
    const int grpB = (wv < 8);
    const int nt2 = grpB ? wv : (wv - 8);
    const int mtA = grpB ? 0 : 2;
    const int mtB = 1;
    const int oc2 = nt2 * 16 + (ln & 15);
    int pybA, pybB;
    {
      int pA = mtA * 16 + (ln & 15);
      int pB = mtB * 16 + (ln & 15);
      pybA = (pA < 36) ? ((pA / 6) * 8 + (pA % 6)) : 64;
      pybB = (pB / 6) * 8 + (pB % 6);
    }
    float cur2[2][4], vol2[2][4];
    #pragma unroll
    for (int m = 0; m < 2; ++m) {
      int mt = m ? mtB : mtA;
      bool use = (m == 0) || grpB;
      #pragma unroll
      for (int r = 0; r < 4; ++r) {
        int p = mt * 16 + ((ln >> 4) << 2) + r;
        if (use && p < 36) {
          cur2[m][r] = c2sg[((1 * 32 + b) * 128 + oc2) * 36 + p];
          vol2[m][r] = c2sg[((2 * 32 + b) * 128 + oc2) * 36 + p];
        } else { cur2[m][r] = 0.f; vol2[m][r] = 0.f; }
      }
    }
    if (tid < 128) b2L[tid] = b2g[tid];
    if (tid < 640) ((unsigned*)s1b)[64 * 32 + tid] = 0u;
    __syncthreads();

    for (int t = 0; t < 100; ++t) {
      if (tid < 100) xt[tid] = input[(b * 100 + tid) * 100 + t];
      __syncthreads();

      #pragma unroll
      for (int j = 0; j < 4; ++j) {
        int pos = pos0 + 16 * j;
        int y = pos >> 3, x = pos & 7;
        float psp = b1r;
        #pragma unroll
        for (int kk = 0; kk < 9; ++kk) {
          int ky = kk / 3, kx = kk - ky * 3;
          psp = fmaf(xt[(y + ky) * 10 + x + kx], w1r[kk], psp);
        }
        float cur = 0.5f * cur1[j] + psp;
        float vol = 0.75f * vol1[j] * (1.f - sp1[j]) + cur;
        float sp  = (vol > VTH) ? 1.f : 0.f;
        cur1[j] = cur; vol1[j] = vol; sp1[j] = sp;
        unsigned short bits = (vol > VTH) ? (unsigned short)0x3C00 : (unsigned short)0;
        int byte = ((pos << 7) + (co << 1)) ^ ((pos & 7) << 4);
        *(unsigned short*)((char*)s1b + byte) = bits;
      }
      __syncthreads();

      // conv2 MFMA (f16 scaled hi/lo split)
      {
        f32x4 acchA = {0,0,0,0}, acclA = {0,0,0,0};
        f32x4 acchB = {0,0,0,0}, acclB = {0,0,0,0};
        const int lnq16 = (ln >> 4) << 4;
        if (grpB) {
          #pragma unroll
          for (int kt = 0; kt < 18; ++kt) {
            const int tap = kt >> 1;
            const int dpos = (tap / 3) * 8 + (tap % 3);
            const int c0b = ((kt & 1) << 6) + lnq16;
            int posA = pybA + dpos, posB = pybB + dpos;
            int abA = ((posA << 7) + c0b) ^ ((posA & 7) << 4);
            int abB = ((posB << 7) + c0b) ^ ((posB & 7) << 4);
            half8v a0 = *(const half8v*)((const char*)s1b + abA);
            half8v a1 = *(const half8v*)((const char*)s1b + abB);
            half8v bh = w2h[(((kt << 3) + nt2) << 1) * 64 + ln];
            half8v bl = w2h[((((kt << 3) + nt2) << 1) + 1) * 64 + ln];
            acchA = __builtin_amdgcn_mfma_f32_16x16x32_f16(a0, bh, acchA, 0, 0, 0);
            acclA = __builtin_amdgcn_mfma_f32_16x16x32_f16(a0, bl, acclA, 0, 0, 0);
            acchB = __builtin_amdgcn_mfma_f32_16x16x32_f16(a1, bh, acchB, 0, 0, 0);
            acclB = __builtin_amdgcn_mfma_f32_16x16x32_f16(a1, bl, acclB, 0, 0, 0);
          }
        } else {
          #pragma unroll
          for (int kt = 0; kt < 18; ++kt) {
            const int tap = kt >> 1;
            const int dpos = (tap / 3) * 8 + (tap % 3);
            const int c0b = ((kt & 1) << 6) + lnq16;
            int posA = pybA + dpos;
            int abA = ((posA << 7) + c0b) ^ ((posA & 7) << 4);
            half8v a0 = *(const half8v*)((const char*)s1b + abA);
            half8v bh = w2h[(((kt << 3) + nt2) << 1) * 64 + ln];
            half8v bl = w2h[((((kt << 3) + nt2) << 1) + 1) * 64 + ln];
            acchA = __builtin_amdgcn_mfma_f32_16x16x32_f16(a0, bh, acchA, 0, 0, 0);
            acclA = __builtin_amdgcn_mfma_f32_16x16x32_f16(a0, bl, acclA, 0, 0, 0);
          }
        }
        float bias2 = b2L[oc2];
        #pragma unroll
        for (int m = 0; m < 2; ++m) {
          if (m == 1 && !grpB) break;
          int mt = m ? mtB : mtA;
          #pragma unroll
          for (int r = 0; r < 4; ++r) {
            int p = mt * 16 + ((ln >> 4) << 2) + r;
            if (p < 36) {
              float hi = m ? acchB[r] : acchA[r];
              float lo = m ? acclB[r] : acclA[r];
              float psp = hi + 0.000244140625f * lo + bias2;
              float spo = (vol2[m][r] > VTH) ? 1.f : 0.f;
              float cur = 0.5f * cur2[m][r] + psp;
              float vol = 0.75f * vol2[m][r] * (1.f - spo) + cur;
              cur2[m][r] = cur; vol2[m][r] = vol;
              s2b[p * 128 + oc2] = (vol > VTH) ? (unsigned short)0x3C00 : (unsigned short)0;
            }
          }
        }
      }
      __syncthreads();

      // pool: spike-count nibbles (exact: pooled value = n * 0.25)
      if (tid < 576) {
        int pp = tid >> 6, c0 = 2 * (tid & 63);
        int sy = (pp / 3) * 2, sx = (pp % 3) * 2;
        int n0 = (s2b[(sy * 6 + sx) * 128 + c0] != 0) + (s2b[(sy * 6 + sx + 1) * 128 + c0] != 0)
               + (s2b[((sy + 1) * 6 + sx) * 128 + c0] != 0) + (s2b[((sy + 1) * 6 + sx + 1) * 128 + c0] != 0);
        int c1 = c0 + 1;
        int n1 = (s2b[(sy * 6 + sx) * 128 + c1] != 0) + (s2b[(sy * 6 + sx + 1) * 128 + c1] != 0)
               + (s2b[((sy + 1) * 6 + sx) * 128 + c1] != 0) + (s2b[((sy + 1) * 6 + sx + 1) * 128 + c1] != 0);
        p2nb[pp * 128 + c0] = (unsigned char)n0;
        p2nb[pp * 128 + c1] = (unsigned char)n1;
      }
      __syncthreads();
      if (tid < 144) {
        unsigned dwv = 0;
        #pragma unroll
        for (int j = 0; j < 8; ++j)
          dwv |= ((unsigned)p2nb[8 * tid + j] & 0xFu) << (4 * j);
        p2g[(b * 100 + t) * 144 + tid] = dwv;
      }
      __threadfence();
      __syncthreads();
      if (tid == 0)
        __hip_atomic_store(&flagA[b * 100 + t], 1u, __ATOMIC_RELEASE, __HIP_MEMORY_SCOPE_AGENT);
    }
  } else if (role == 1 || role == 2) {
    // ================= STAGE B / B': conv3 half (oc half*128 ..) ============
    const int half = role - 1;
    const float4* w3p = (const float4*)(ws + W3P_OFF);
    __shared__ float p2L[1152];
    __shared__ unsigned short cidxB[1152];
    __shared__ int ccntB[16];
    __shared__ __align__(16) f32x4 scrB[16 * 64];
    __shared__ float b3L[128];

    float c3sp = 0.f, c3cur = 0.f, c3vol = 0.f;
    if (tid < 128) {
      int oc = half * 128 + tid;
      c3sp  = c3sg[(0 * 32 + b) * 256 + oc];
      c3cur = c3sg[(1 * 32 + b) * 256 + oc];
      c3vol = c3sg[(2 * 32 + b) * 256 + oc];
      b3L[tid] = b3g[oc];
    }
    __syncthreads();

    for (int t = 0; t < 100; ++t) {
      // wait producer A
      {
        unsigned* f = &flagA[b * 100 + t];
        int guard = 0;
        while (__hip_atomic_load(f, __ATOMIC_ACQUIRE, __HIP_MEMORY_SCOPE_AGENT) == 0u) {
          __builtin_amdgcn_s_sleep(2);
          if (++guard > 1000000) break;
        }
      }
      if (tid < 576) {
        unsigned dwv = p2g[(b * 100 + t) * 144 + (tid >> 2)];
        int sh = (tid & 3) * 8;
        p2L[2 * tid]     = 0.25f * (float)((dwv >> sh) & 0xF);
        p2L[2 * tid + 1] = 0.25f * (float)((dwv >> (sh + 4)) & 0xF);
      }
      __syncthreads();

      // compaction: 16 waves x 72-elem segments
      {
        int base = wv * 72;
        float e0 = p2L[base + ln];
        unsigned long long bl0 = __ballot(e0 != 0.f);
        if (e0 != 0.f)
          cidxB[base + __popcll(bl0 & ((1ull << ln) - 1ull))] = (unsigned short)(base + ln);
        int cnt0 = __popcll(bl0);
        float e1 = (ln < 8) ? p2L[base + 64 + ln] : 0.f;
        unsigned long long bl1 = __ballot((ln < 8) && (e1 != 0.f));
        if (ln < 8 && e1 != 0.f)
          cidxB[base + cnt0 + __popcll(bl1 & ((1ull << ln) - 1ull))] = (unsigned short)(base + 64 + ln);
        if (ln == 0) ccntB[wv] = cnt0 + __popcll(bl1);
      }
      __syncthreads();

      // stream: pairs (lane jj=ln>>5 handles nonzeros i+jj), half-columns 512B
      {
        int n = ccntB[wv], base = wv * 72;
        int jj = ln >> 5, q = ln & 31;
        f32x4 a = {0.f, 0.f, 0.f, 0.f};
        for (int i = jj; i < n; i += 2) {
          int k = cidxB[base + i];
          float v = p2L[k];
          float4 w = w3p[k * 64 + (half << 5) + q];
          a.x = fmaf(v, w.x, a.x); a.y = fmaf(v, w.y, a.y);
          a.z = fmaf(v, w.z, a.z); a.w = fmaf(v, w.w, a.w);
        }
        scrB[wv * 64 + ln] = a;
      }
      __syncthreads();

      // reduce + LIF3 + ballot spike bits + publish
      if (tid < 128) {
        const float* sf = (const float*)scrB;
        float s = b3L[tid];
        #pragma unroll
        for (int ks = 0; ks < 16; ++ks)
          s += sf[ks * 256 + tid] + sf[ks * 256 + 128 + tid];
        float cur = 0.5f * c3cur + s;
        float vol = 0.75f * c3vol * (1.f - c3sp) + cur;
        float sp  = (vol > VTH) ? 1.f : 0.f;
        c3cur = cur; c3vol = vol; c3sp = sp;
        unsigned long long bl = __ballot(sp != 0.f);
        if (ln == 0) {
          sp3g[(b * 100 + t) * 8 + half * 4 + wv * 2]     = (unsigned)bl;
          sp3g[(b * 100 + t) * 8 + half * 4 + wv * 2 + 1] = (unsigned)(bl >> 32);
        }
      }
      __threadfence();
      __syncthreads();
      if (tid == 0) {
        unsigned* f = half ? &flagB2[b * 100 + t] : &flagB[b * 100 + t];
        __hip_atomic_store(f, 1u, __ATOMIC_RELEASE, __HIP_MEMORY_SCOPE_AGENT);
      }
    }
  } else {
    // ================= STAGE C: tc + rec + fc1 + fc2/acc ====================
    const float4* tcp  = (const float4*)(ws + TCP_OFF);
    const float4* recp = (const float4*)(ws + RECP_OFF);
    const float4* fc1p = (const float4*)(ws + FC1P_OFF);

    __shared__ __align__(16) f32x4 scrT[12 * 64];
    __shared__ __align__(16) f32x4 scrR[4 * 64];
    __shared__ __align__(16) f32x4 scrF[16 * 64];
    __shared__ unsigned short cidxT[768];
    __shared__ unsigned short cidxR[256];
    __shared__ unsigned short cidxF[256];
    __shared__ int ccntT[12], ccntR[4];
    __shared__ unsigned long long histB[12];   // [3 rows][4 chunks]
    __shared__ unsigned long long rspB[4];
    __shared__ float tcbL[768], recbL[256], fc1bL[128];
    __shared__ float fc2wL[256], maskL[128], tswL[100];
    __shared__ float accv[2];
    __shared__ float wpart[2][2];

    float tccur = 0.f, tcvol = 0.f, tcsp = 0.f;
    float rcur = 0.f, rvol = 0.f, rspv = 0.f;
    float fcur = 0.f, fvol = 0.f, fsp = 0.f;
    if (tid < 256) {
      tcsp  = tcsg[(0 * 32 + b) * 256 + tid];
      tccur = tcsg[(1 * 32 + b) * 256 + tid];
      tcvol = tcsg[(2 * 32 + b) * 256 + tid];
      rspv  = rsg[(0 * 32 + b) * 256 + tid];
      rcur  = rsg[(1 * 32 + b) * 256 + tid];
      rvol  = rsg[(2 * 32 + b) * 256 + tid];
      recbL[tid] = recbg[tid];
      tcbL[tid]       = tcbg[tid];
      tcbL[256 + tid] = tcbg[256 + tid];
      tcbL[512 + tid] = tcbg[512 + tid];
      unsigned long long bl = __ballot(rspv != 0.f);
      if (ln == 0) rspB[wv] = bl;
    }
    if (tid < 128) {
      fsp   = fsg[(0 * 32 + b) * 128 + tid];
      fcur  = fsg[(1 * 32 + b) * 128 + tid];
      fvol  = fsg[(2 * 32 + b) * 128 + tid];
      fc1bL[tid] = fc1bg[tid];
      maskL[tid] = maskg[b * 128 + tid];
      fc2wL[tid]       = fc2wg[tid];
      fc2wL[128 + tid] = fc2wg[128 + tid];
    }
    if (tid < 100) tswL[tid] = tswg[tid];
    if (tid < 12) histB[tid] = 0ull;
    if (tid == 0) { accv[0] = 0.f; accv[1] = 0.f; }
    __syncthreads();

    for (int t = 0; t < 100; ++t) {
      const int tm3 = t % 3;
      const int bt = b * 100 + t;

      // wait both conv3 halves
      {
        unsigned* f1 = &flagB[bt];
        unsigned* f2 = &flagB2[bt];
        int guard = 0;
        while (__hip_atomic_load(f1, __ATOMIC_ACQUIRE, __HIP_MEMORY_SCOPE_AGENT) == 0u ||
               __hip_atomic_load(f2, __ATOMIC_ACQUIRE, __HIP_MEMORY_SCOPE_AGENT) == 0u) {
          __builtin_amdgcn_s_sleep(2);
          if (++guard > 1000000) break;
        }
      }
      __syncthreads();

      // phase 1: tc compaction (waves 0-11) + rec compaction (waves 12-15)
      if (wv < 12) {
        int kk = wv >> 2, g = wv & 3;
        unsigned long long m;
        if (kk == 2) {
          unsigned lo = sp3g[bt * 8 + g * 2];
          unsigned hi = sp3g[bt * 8 + g * 2 + 1];
          m = ((unsigned long long)hi << 32) | lo;
          if (ln == 0) histB[tm3 * 4 + g] = m;
        } else {
          int row = tm3 + 1 + kk; if (row >= 3) row -= 3;
          m = histB[row * 4 + g];
        }
        if ((m >> ln) & 1ull)
          cidxT[wv * 64 + __popcll(m & ((1ull << ln) - 1ull))] = (unsigned short)(wv * 64 + ln);
        if (ln == 0) ccntT[wv] = __popcll(m);
      } else {
        int g = wv - 12;
        unsigned long long m = rspB[g];
        if ((m >> ln) & 1ull)
          cidxR[g * 64 + __popcll(m & ((1ull << ln) - 1ull))] = (unsigned short)(g * 64 + ln);
        if (ln == 0) ccntR[g] = __popcll(m);
      }
      __syncthreads();

      // phase 2: tc stream (waves 0-11) || rec stream (waves 12-15)
      if (wv < 12) {
        int n = ccntT[wv];
        f32x4 a0 = {0,0,0,0}, a1 = {0,0,0,0};
        int i = 0;
        for (; i + 2 <= n; i += 2) {
          int k0 = cidxT[wv * 64 + i], k1 = cidxT[wv * 64 + i + 1];
          float4 w0 = tcp[k0 * 64 + ln];
          float4 w1 = tcp[k1 * 64 + ln];
          a0.x += w0.x; a0.y += w0.y; a0.z += w0.z; a0.w += w0.w;
          a1.x += w1.x; a1.y += w1.y; a1.z += w1.z; a1.w += w1.w;
        }
        if (i < n) {
          float4 w0 = tcp[cidxT[wv * 64 + i] * 64 + ln];
          a0.x += w0.x; a0.y += w0.y; a0.z += w0.z; a0.w += w0.w;
        }
        f32x4 a = {a0.x + a1.x, a0.y + a1.y, a0.z + a1.z, a0.w + a1.w};
        scrT[wv * 64 + ln] = a;
      } else {
        int g = wv - 12;
        int n = ccntR[g];
        f32x4 a0 = {0,0,0,0}, a1 = {0,0,0,0};
        int i = 0;
        for (; i + 2 <= n; i += 2) {
          int c0 = cidxR[g * 64 + i], c1 = cidxR[g * 64 + i + 1];
          float4 w0 = recp[c0 * 64 + ln];
          float4 w1 = recp[c1 * 64 + ln];
          a0.x += w0.x; a0.y += w0.y; a0.z += w0.z; a0.w += w0.w;
          a1.x += w1.x; a1.y += w1.y; a1.z += w1.z; a1.w += w1.w;
        }
        if (i < n) {
          float4 w0 = recp[cidxR[g * 64 + i] * 64 + ln];
          a0.x += w0.x; a0.y += w0.y; a0.z += w0.z; a0.w += w0.w;
        }
        f32x4 a = {a0.x + a1.x, a0.y + a1.y, a0.z + a1.z, a0.w + a1.w};
        scrR[g * 64 + ln] = a;
      }
      __syncthreads();

      // phase 3: tc reduce + LIF4 -> s4 ; rec reduce + LIF5 -> s5 bits
      if (tid < 256) {
        const float* sT = (const float*)scrT;
        float s = 0.f;
        #pragma unroll
        for (int w = 0; w < 12; ++w) s += sT[w * 256 + tid];
        #pragma unroll
        for (int kk = 0; kk < 3; ++kk)
          if (t >= 2 - kk) s += tcbL[kk * 256 + tid];
        float cur4 = 0.5f * tccur + s;
        float vol4 = 0.75f * tcvol * (1.f - tcsp) + cur4;
        float sp4  = (vol4 > VTH) ? 1.f : 0.f;
        tccur = cur4; tcvol = vol4; tcsp = sp4;

        const float* sR = (const float*)scrR;
        float r = sp4 + recbL[tid];
        #pragma unroll
        for (int g = 0; g < 4; ++g) r += sR[g * 256 + tid];
        float cur5 = 0.5f * rcur + r;
        float vol5 = 0.75f * rvol * (1.f - rspv) + cur5;
        float sp5  = (vol5 > VTH) ? 1.f : 0.f;
        rcur = cur5; rvol = vol5; rspv = sp5;
        unsigned long long bl = __ballot(sp5 != 0.f);
        if (ln == 0) rspB[wv] = bl;
      }
      __syncthreads();

      // phase 4: fc1 stream, 16 waves x 16-k segments, wave-local compaction
      {
        unsigned mask = (unsigned)((rspB[wv >> 2] >> ((wv & 3) * 16)) & 0xFFFFull);
        if (ln < 16) {
          if ((mask >> ln) & 1u)
            cidxF[wv * 16 + __popc(mask & ((1u << ln) - 1u))] = (unsigned short)(wv * 16 + ln);
        }
        int nF = __popc(mask);
        int jj = ln >> 5, q = ln & 31;
        f32x4 a = {0.f, 0.f, 0.f, 0.f};
        for (int i = jj; i < nF; i += 2) {
          int k = cidxF[wv * 16 + i];
          float4 w = fc1p[k * 32 + q];
          a.x += w.x; a.y += w.y; a.z += w.z; a.w += w.w;
        }
        scrF[wv * 64 + ln] = a;
      }
      __syncthreads();

      // phase 5: fc1 reduce + dropout LIF6 + fc2 partial
      if (tid < 128) {
        const float* sF = (const float*)scrF;
        float s = fc1bL[tid];
        #pragma unroll
        for (int w = 0; w < 16; ++w)
          s += sF[w * 256 + tid] + sF[w * 256 + 128 + tid];
        float cur = (0.5f * fcur + s) * maskL[tid];
        float vol = 0.75f * fvol * (1.f - fsp) + cur;
        float sp  = (vol > VTH) ? 1.f : 0.f;
        fcur = cur; fvol = vol; fsp = sp;
        float v0 = sp * fc2wL[tid];
        float v1 = sp * fc2wL[128 + tid];
        #pragma unroll
        for (int off = 32; off > 0; off >>= 1) {
          v0 += __shfl_down(v0, off);
          v1 += __shfl_down(v1, off);
        }
        if (ln == 0) { wpart[wv][0] = v0; wpart[wv][1] = v1; }
      }
      __syncthreads();
      if (tid == 0) {
        float wt = tswL[t];
        accv[0] += wt * (wpart[0][0] + wpart[1][0]);
        accv[1] += wt * (wpart[0][1] + wpart[1][1]);
      }
    }
    __syncthreads();
    if (tid < 2) out[b * 2 + tid] = accv[tid];
  }
}

// ---------------------------------------------------------------------------
// R7 monolithic fallback (used when ws_size < WS_NEED_BYTES)
// ---------------------------------------------------------------------------
__global__ __launch_bounds__(1024, 4) void snn_main(
    const float* __restrict__ input, const float* __restrict__ w1g,
    const float* __restrict__ b1g, const float* __restrict__ b2g,
    const float* __restrict__ b3g, const float* __restrict__ tcbg,
    const float* __restrict__ recbg, const float* __restrict__ fc1bg,
    const float* __restrict__ fc2wg, const float* __restrict__ tswg,
    const float* __restrict__ maskg,
    const float* __restrict__ c1sg, const float* __restrict__ c2sg,
    const float* __restrict__ c3sg, const float* __restrict__ tcsg,
    const float* __restrict__ rsg, const float* __restrict__ fsg,
    const float* __restrict__ ws, float* __restrict__ out)
{
  const half8v* w2h  = (const half8v*)ws;
  const float4* w3p  = (const float4*)(ws + W3P_OFF);
  const float4* tcp  = (const float4*)(ws + TCP_OFF);
  const float4* recp = (const float4*)(ws + RECP_OFF);
  const float4* fc1p = (const float4*)(ws + FC1P_OFF);

  const int b   = blockIdx.x;
  const int tid = threadIdx.x;
  const int wv  = tid >> 6;
  const int ln  = tid & 63;

  __shared__ __align__(16) float scratch[4096];
  __shared__ __align__(16) unsigned short s1b[84 * 64];
  __shared__ unsigned short s2b[36 * 128];
  __shared__ float p2f[1152];
  __shared__ float xt[100];
  __shared__ float histf[768];
  __shared__ float s4v[256];
  __shared__ float c3cur[256], c3vol[256], c3sp[256];
  __shared__ float tccur[256], tcvol[256], tcsp[256];
  __shared__ float rcur[256],  rvol[256],  rsp[256];
  __shared__ float fcur[128],  fvol[128],  fsp[128];
  __shared__ float b3L[256], tcbL[768], recbL[256], fc1bL[128];
  __shared__ float fc2wL[256], maskL[128], tswL[100], b2L[128];
  __shared__ float accv[2];
  __shared__ float wpart[2][2];

  const int co = ln, pos0 = wv;
  float w1r[9];
  #pragma unroll
  for (int k = 0; k < 9; ++k) w1r[k] = w1g[co * 9 + k];
  const float b1r = b1g[co];
  float sp1[4], cur1[4], vol1[4];
  #pragma unroll
  for (int j = 0; j < 4; ++j) {
    int pos = pos0 + 16 * j;
    sp1[j]  = c1sg[((0 * 32 + b) * 64 + co) * 64 + pos];
    cur1[j] = c1sg[((1 * 32 + b) * 64 + co) * 64 + pos];
    vol1[j] = c1sg[((2 * 32 + b) * 64 + co) * 64 + pos];
  }
  const int grpB = (wv < 8);
  const int nt2 = grpB ? wv : (wv - 8);
  const int mtA = grpB ? 0 : 2;
  const int mtB = 1;
  const int oc2 = nt2 * 16 + (ln & 15);
  int pybA, pybB;
  {
    int pA = mtA * 16 + (ln & 15);
    int pB = mtB * 16 + (ln & 15);
    pybA = (pA < 36) ? ((pA / 6) * 8 + (pA % 6)) : 64;
    pybB = (pB / 6) * 8 + (pB % 6);
  }
  float cur2[2][4], vol2[2][4];
  #pragma unroll
  for (int m = 0; m < 2; ++m) {
    int mt = m ? mtB : mtA;
    bool use = (m == 0) || grpB;
    #pragma unroll
    for (int r = 0; r < 4; ++r) {
      int p = mt * 16 + ((ln >> 4) << 2) + r;
      if (use && p < 36) {
        cur2[m][r] = c2sg[((1 * 32 + b) * 128 + oc2) * 36 + p];
        vol2[m][r] = c2sg[((2 * 32 + b) * 128 + oc2) * 36 + p];
      } else { cur2[m][r] = 0.f; vol2[m][r] = 0.f; }
    }
  }
  if (tid < 256) {
    c3sp[tid]  = c3sg[(0 * 32 + b) * 256 + tid];
    c3cur[tid] = c3sg[(1 * 32 + b) * 256 + tid];
    c3vol[tid] = c3sg[(2 * 32 + b) * 256 + tid];
    tcsp[tid]  = tcsg[(0 * 32 + b) * 256 + tid];
    tccur[tid] = tcsg[(1 * 32 + b) * 256 + tid];
    tcvol[tid] = tcsg[(2 * 32 + b) * 256 + tid];
    rsp[tid]   = rsg[(0 * 32 + b) * 256 + tid];
    rcur[tid]  = rsg[(1 * 32 + b) * 256 + tid];
    rvol[tid]  = rsg[(2 * 32 + b) * 256 + tid];
    b3L[tid]   = b3g[tid];
    recbL[tid] = recbg[tid];
    tcbL[tid]       = tcbg[tid];
    tcbL[256 + tid] = tcbg[256 + tid];
    tcbL[512 + tid] = tcbg[512 + tid];
    histf[tid] = 0.f; histf[256 + tid] = 0.f; histf[512 + tid] = 0.f;
  }
  if (tid < 128) {
    fsp[tid]   = fsg[(0 * 32 + b) * 128 + tid];
    fcur[tid]  = fsg[(1 * 32 + b) * 128 + tid];
    fvol[tid]  = fsg[(2 * 32 + b) * 128 + tid];
    fc1bL[tid] = fc1bg[tid];
    maskL[tid] = maskg[b * 128 + tid];
    b2L[tid]   = b2g[tid];
    fc2wL[tid]       = fc2wg[tid];
    fc2wL[128 + tid] = fc2wg[128 + tid];
  }
  if (tid < 100) tswL[tid] = tswg[tid];
  if (tid < 640) ((unsigned*)s1b)[64 * 32 + tid] = 0u;
  if (tid == 0) { accv[0] = 0.f; accv[1] = 0.f; }
  __syncthreads();

  for (int t = 0; t < 100; ++t) {
    const int tm3 = t % 3;
    if (tid < 100) xt[tid] = input[(b * 100 + tid) * 100 + t];
    __syncthreads();
    #pragma unroll
    for (int j = 0; j < 4; ++j) {
      int pos = pos0 + 16 * j;
      int y = pos >> 3, x = pos & 7;
      float psp = b1r;
      #pragma unroll
      for (int kk = 0; kk < 9; ++kk) {
        int ky = kk / 3, kx = kk - ky * 3;
        psp = fmaf(xt[(y + ky) * 10 + x + kx], w1r[kk], psp);
      }
      float cur = 0.5f * cur1[j] + psp;
      float vol = 0.75f * vol1[j] * (1.f - sp1[j]) + cur;
      float sp  = (vol > VTH) ? 1.f : 0.f;
      cur1[j] = cur; vol1[j] = vol; sp1[j] = sp;
      unsigned short bits = (vol > VTH) ? (unsigned short)0x3C00 : (unsigned short)0;
      int byte = ((pos << 7) + (co << 1)) ^ ((pos & 7) << 4);
      *(unsigned short*)((char*)s1b + byte) = bits;
    }
    __syncthreads();
    {
      f32x4 acchA = {0,0,0,0}, acclA = {0,0,0,0};
      f32x4 acchB = {0,0,0,0}, acclB = {0,0,0,0};
      const int lnq16 = (ln >> 4) << 4;
      if (grpB) {
        #pragma unroll
        for (int kt = 0; kt < 18; ++kt) {
          const int tap = kt >> 1;
          const int dpos = (tap / 3) * 8 + (tap % 3);
          const int c0b = ((kt & 1) << 6) + lnq16;
          int posA = pybA + dpos, posB = pybB + dpos;
          int abA = ((posA << 7) + c0b) ^ ((posA & 7) << 4);
          int abB = ((posB << 7) + c0b) ^ ((posB & 7) << 4);
          half8v a0 = *(const half8v*)((const char*)s1b + abA);
          half8v a1 = *(const half8v*)((const char*)s1b + abB);
          half8v bh = w2h[(((kt << 3) + nt2) << 1) * 64 + ln];
          half8v bl = w2h[((((kt << 3) + nt2) << 1) + 1) * 64 + ln];
          acchA = __builtin_amdgcn_mfma_f32_16x16x32_f16(a0, bh, acchA, 0, 0, 0);
          acclA = __builtin_amdgcn_mfma_f32_16x16x32_f16(a0, bl, acclA, 0, 0, 0);
          acchB = __builtin_amdgcn_mfma_f32_16x16x32_f16(a1, bh, acchB, 0, 0, 0);
          acclB = __builtin_amdgcn_mfma_f32_16x16x32_f16(a1, bl, acclB, 0, 0, 0);
        }
      } else {
        #pragma unroll
        for (int kt = 0; kt < 18; ++kt) {
          const int tap = kt >> 1;
          const int dpos = (tap / 3) * 8 + (tap % 3);
          const int c0b = ((kt & 1) << 6) + lnq16;
          int posA = pybA + dpos;
          int abA = ((posA << 7) + c0b) ^ ((posA & 7) << 4);
          half8v a0 = *(const half8v*)((const char*)s1b + abA);
          half8v bh = w2h[(((kt << 3) + nt2) << 1) * 64 + ln];
          half8v bl = w2h[((((kt << 3) + nt2) << 1) + 1) * 64 + ln];
          acchA = __builtin_amdgcn_mfma_f32_16x16x32_f16(a0, bh, acchA, 0, 0, 0);
          acclA = __builtin_amdgcn_mfma_f32_16x16x32_f16(a0, bl, acclA, 0, 0, 0);
        }
      }
      float bias2 = b2L[oc2];
      #pragma unroll
      for (int m = 0; m < 2; ++m) {
        if (m == 1 && !grpB) break;
        int mt = m ? mtB : mtA;
        #pragma unroll
        for (int r = 0; r < 4; ++r) {
          int p = mt * 16 + ((ln >> 4) << 2) + r;
          if (p < 36) {
            float hi = m ? acchB[r] : acchA[r];
            float lo = m ? acclB[r] : acclA[r];
            float psp = hi + 0.000244140625f * lo + bias2;
            float spo = (vol2[m][r] > VTH) ? 1.f : 0.f;
            float cur = 0.5f * cur2[m][r] + psp;
            float vol = 0.75f * vol2[m][r] * (1.f - spo) + cur;
            cur2[m][r] = cur; vol2[m][r] = vol;
            s2b[p * 128 + oc2] = (vol > VTH) ? (unsigned short)0x3C00 : (unsigned short)0;
          }
        }
      }
    }
    __syncthreads();
    {
      int c = tid & 127, pp = tid >> 7;
      int sy = (pp / 3) * 2, sx = (pp % 3) * 2;
      float v = h2f(s2b[(sy * 6 + sx) * 128 + c]) + h2f(s2b[(sy * 6 + sx + 1) * 128 + c])
              + h2f(s2b[((sy + 1) * 6 + sx) * 128 + c]) + h2f(s2b[((sy + 1) * 6 + sx + 1) * 128 + c]);
      p2f[pp * 128 + c] = 0.25f * v;
      if (tid < 128) {
        float v8 = h2f(s2b[(4 * 6 + 4) * 128 + c]) + h2f(s2b[(4 * 6 + 5) * 128 + c])
                 + h2f(s2b[(5 * 6 + 4) * 128 + c]) + h2f(s2b[(5 * 6 + 5) * 128 + c]);
        p2f[8 * 128 + c] = 0.25f * v8;
      }
    }
    __syncthreads();
    {
      int ocq = tid & 63, ks = tid >> 6;
      float4 a = {0.f, 0.f, 0.f, 0.f};
      const float4* wrow = w3p + (ks * 72) * 64 + ocq;
      const float* prow = p2f + ks * 72;
      #pragma unroll 8
      for (int i = 0; i < 72; ++i) {
        float pv = prow[i];
        if (pv != 0.f) {
          float4 w = wrow[i * 64];
          a.x = fmaf(pv, w.x, a.x); a.y = fmaf(pv, w.y, a.y);
          a.z = fmaf(pv, w.z, a.z); a.w = fmaf(pv, w.w, a.w);
        }
      }
      ((float4*)scratch)[tid] = a;
    }
    __syncthreads();
    if (tid < 256) {
      int d = tid;
      float s = b3L[d];
      #pragma unroll
      for (int ks = 0; ks < 16; ++ks) s += scratch[ks * 256 + d];
      float cur = 0.5f * c3cur[d] + s;
      float vol = 0.75f * c3vol[d] * (1.f - c3sp[d]) + cur;
      float sp  = (vol > VTH) ? 1.f : 0.f;
      c3cur[d] = cur; c3vol[d] = vol; c3sp[d] = sp;
      histf[tm3 * 256 + d] = sp;
    }
    __syncthreads();
    {
      int dq = tid & 63, ks = tid >> 6;
      float4 a = {0.f, 0.f, 0.f, 0.f};
      const float4* wrow = tcp + (ks * 48) * 64 + dq;
      #pragma unroll 8
      for (int i = 0; i < 48; ++i) {
        int k = ks * 48 + i;
        int kk = k >> 8;
        int vv = tm3 + 1 + kk; if (vv >= 3) vv -= 3;
        float hv = histf[(vv << 8) + (k & 255)];
        if (hv != 0.f) {
          float4 w = wrow[i * 64];
          a.x = fmaf(hv, w.x, a.x); a.y = fmaf(hv, w.y, a.y);
          a.z = fmaf(hv, w.z, a.z); a.w = fmaf(hv, w.w, a.w);
        }
      }
      ((float4*)scratch)[tid] = a;
    }
    __syncthreads();
    if (tid < 256) {
      int d = tid;
      float s = 0.f;
      #pragma unroll
      for (int ks = 0; ks < 16; ++ks) s += scratch[ks * 256 + d];
      #pragma unroll
      for (int kk = 0; kk < 3; ++kk)
        if (t >= 2 - kk) s += tcbL[kk * 256 + d];
      float cur = 0.5f * tccur[d] + s;
      float vol = 0.75f * tcvol[d] * (1.f - tcsp[d]) + cur;
      float sp  = (vol > VTH) ? 1.f : 0.f;
      tccur[d] = cur; tcvol[d] = vol; tcsp[d] = sp;
      s4v[d] = sp;
    }
    __syncthreads();
    {
      int dq = tid & 63, ks = tid >> 6;
      float4 a = {0.f, 0.f, 0.f, 0.f};
      const float4* wrow = recp + (ks * 16) * 64 + dq;
      const float* hr = rsp + ks * 16;
      #pragma unroll
      for (int i = 0; i < 16; ++i) {
        float hv = hr[i];
        if (hv != 0.f) {
          float4 w = wrow[i * 64];
          a.x = fmaf(hv, w.x, a.x); a.y = fmaf(hv, w.y, a.y);
          a.z = fmaf(hv, w.z, a.z); a.w = fmaf(hv, w.w, a.w);
        }
      }
      ((float4*)scratch)[tid] = a;
    }
    __syncthreads();
    if (tid < 256) {
      int d = tid;
      float s = s4v[d] + recbL[d];
      #pragma unroll
      for (int ks = 0; ks < 16; ++ks) s += scratch[ks * 256 + d];
      float cur = 0.5f * rcur[d] + s;
      float vol = 0.75f * rvol[d] * (1.f - rsp[d]) + cur;
      float sp  = (vol > VTH) ? 1.f : 0.f;
      rcur[d] = cur; rvol[d] = vol; rsp[d] = sp;
    }
    __syncthreads();
    {
      int dq = tid & 31, ks = tid >> 5;
      float4 a = {0.f, 0.f, 0.f, 0.f};
      const float4* wrow = fc1p + (ks * 8) * 32 + dq;
      const float* hr = rsp + ks * 8;
      #pragma unroll
      for (int i = 0; i < 8; ++i) {
        float hv = hr[i];
        if (hv != 0.f) {
          float4 w = wrow[i * 32];
          a.x = fmaf(hv, w.x, a.x); a.y = fmaf(hv, w.y, a.y);
          a.z = fmaf(hv, w.z, a.z); a.w = fmaf(hv, w.w, a.w);
        }
      }
      ((float4*)scratch)[tid] = a;
    }
    __syncthreads();
    if (tid < 128) {
      int d = tid;
      float s = fc1bL[d];
      #pragma unroll
      for (int ks = 0; ks < 32; ++ks) s += scratch[ks * 128 + d];
      float cur = (0.5f * fcur[d] + s) * maskL[d];
      float vol = 0.75f * fvol[d] * (1.f - fsp[d]) + cur;
      float sp  = (vol > VTH) ? 1.f : 0.f;
      fcur[d] = cur; fvol[d] = vol; fsp[d] = sp;
      float v0 = sp * fc2wL[d];
      float v1 = sp * fc2wL[128 + d];
      #pragma unroll
      for (int off = 32; off > 0; off >>= 1) {
        v0 += __shfl_down(v0, off);
        v1 += __shfl_down(v1, off);
      }
      if ((tid & 63) == 0) { wpart[tid >> 6][0] = v0; wpart[tid >> 6][1] = v1; }
    }
    __syncthreads();
    if (tid == 0) {
      float wt = tswL[t];
      accv[0] += wt * (wpart[0][0] + wpart[1][0]);
      accv[1] += wt * (wpart[0][1] + wpart[1][1]);
    }
  }
  __syncthreads();
  if (tid < 2) out[b * 2 + tid] = accv[tid];
}

extern "C" void kernel_launch(void* const* d_in, const int* in_sizes, int n_in,
                              void* d_out, int out_size, void* d_ws, size_t ws_size,
                              hipStream_t stream) {
  const float* input = (const float*)d_in[0];
  const float* w1    = (const float*)d_in[1];
  const float* b1    = (const float*)d_in[2];
  const float* w2    = (const float*)d_in[3];
  const float* b2    = (const float*)d_in[4];
  const float* w3    = (const float*)d_in[5];
  const float* b3    = (const float*)d_in[6];
  const float* tcw   = (const float*)d_in[7];
  const float* tcb   = (const float*)d_in[8];
  const float* recw  = (const float*)d_in[9];
  const float* recb  = (const float*)d_in[10];
  const float* fc1w  = (const float*)d_in[11];
  const float* fc1b  = (const float*)d_in[12];
  const float* fc2w  = (const float*)d_in[13];
  const float* tsw   = (const float*)d_in[14];
  const float* mask  = (const float*)d_in[15];
  const float* c1s   = (const float*)d_in[16];
  const float* c2s   = (const float*)d_in[17];
  const float* c3s   = (const float*)d_in[18];
  const float* tcs   = (const float*)d_in[19];
  const float* rs    = (const float*)d_in[20];
  const float* fs    = (const float*)d_in[21];
  float* ws   = (float*)d_ws;
  float* outp = (float*)d_out;

  prep_weights<<<WS_FLOATS / 256, 256, 0, stream>>>(w2, w3, tcw, recw, fc1w, ws);
  if (ws_size >= WS_NEED_BYTES) {
    zero_flags<<<(WS_DW_END - FLA_OFF + 255) / 256, 256, 0, stream>>>(ws);
    snn_pipe<<<128, 1024, 0, stream>>>(input, w1, b1, b2, b3, tcb, recb, fc1b,
                                       fc2w, tsw, mask, c1s, c2s, c3s, tcs, rs, fs,
                                       ws, outp);
  } else {
    snn_main<<<32, 1024, 0, stream>>>(input, w1, b1, b2, b3, tcb, recb, fc1b,
                                      fc2w, tsw, mask, c1s, c2s, c3s, tcs, rs, fs,
                                      ws, outp);
  }
}

// Round 10
// 1301.409 us; speedup vs baseline: 4.3432x; 4.3432x over previous
//
#include <hip/hip_runtime.h>

// CUBA Spiking CNN, B=32, T=100.
// R10: two-stage fence-free pipeline (64 blocks).
//  Stage A [0,32):  conv1 + conv2(MFMA f16 hi/lo) + pool -> nibble counts,
//                   published via WRITE-THROUGH relaxed agent atomics;
//                   flag (WT atomic) every 4 steps after s_waitcnt vmcnt(0).
//                   NO __threadfence (R9's L2-writeback storm removed).
//  Stage C [32,64): conv3 computed 4 timesteps per chunk (weights read once
//                   per chunk, dense fmaf — bit-identical to zero-skip),
//                   then per-step LIF3 -> bitmask tc||rec streams -> LIF4/5 ->
//                   fc1 (bitmask) -> LIF6 -> fc2/acc.
// Fallback to R7 monolithic kernel if ws_size too small.

#define VTH 0.5f

// d_ws dword offsets
#define W2P_OFF  0
#define W3P_OFF  73728
#define TCP_OFF  368640
#define RECP_OFF 565248
#define FC1P_OFF 630784
#define WS_FLOATS 663552
#define P2G_OFF   WS_FLOATS                    // 144 dw per (b,t), nibble counts
#define FLA_OFF   (P2G_OFF + 32 * 100 * 144)   // 800 flags (one per 4 steps)
#define FLAGS_N   800
#define WS_DW_END (FLA_OFF + FLAGS_N)
#define WS_NEED_BYTES ((size_t)WS_DW_END * 4)

typedef __attribute__((ext_vector_type(8))) _Float16 half8v;
typedef __attribute__((ext_vector_type(4))) float f32x4;

__device__ inline unsigned short f2h_bits(float x) {
  union { _Float16 h; unsigned short u; } c; c.h = (_Float16)x; return c.u;
}
__device__ inline float h2f(unsigned short u) {
  union { unsigned short u; _Float16 h; } c; c.u = u; return (float)c.h;
}

__global__ __launch_bounds__(256) void prep_weights(
    const float* __restrict__ w2, const float* __restrict__ w3,
    const float* __restrict__ tcw, const float* __restrict__ recw,
    const float* __restrict__ fc1w, float* __restrict__ ws)
{
  int idx = blockIdx.x * 256 + threadIdx.x;
  if (idx < W3P_OFF) {
    int frag = idx >> 8, r = idx & 255;
    int lane = r >> 2, dw = r & 3;
    int half = frag & 1, nt = (frag >> 1) & 7, kt = frag >> 4;
    unsigned out = 0;
    #pragma unroll
    for (int j2 = 0; j2 < 2; ++j2) {
      int j = dw * 2 + j2;
      int oc = nt * 16 + (lane & 15);
      int k = kt * 32 + ((lane >> 4) << 3) + j;
      int c = k & 63, tap = k >> 6;
      float w = w2[(oc * 64 + c) * 9 + tap];
      unsigned short hb = f2h_bits(w);
      unsigned short bits = half ? f2h_bits((w - h2f(hb)) * 4096.f) : hb;
      out |= ((unsigned)bits) << (16 * j2);
    }
    ((unsigned*)ws)[idx] = out;
  } else if (idx < TCP_OFF) {
    int i = idx - W3P_OFF;
    int r = i & 3, ocq = (i >> 2) & 63, k = i >> 8;
    int oc = ocq * 4 + r, c = k & 127, pos9 = k >> 7;
    ws[idx] = w3[(oc * 128 + c) * 9 + pos9];
  } else if (idx < RECP_OFF) {
    int i = idx - TCP_OFF;
    int r = i & 3, dq = (i >> 2) & 63, k = i >> 8;
    int d = dq * 4 + r, c = k & 255, kk = k >> 8;
    ws[idx] = tcw[(kk * 256 + d) * 256 + c];
  } else if (idx < FC1P_OFF) {
    int i = idx - RECP_OFF;
    int r = i & 3, dq = (i >> 2) & 63, c = i >> 8;
    ws[idx] = recw[(dq * 4 + r) * 256 + c];
  } else if (idx < WS_FLOATS) {
    int i = idx - FC1P_OFF;
    int r = i & 3, dq = (i >> 2) & 31, c = i >> 7;
    ws[idx] = fc1w[(dq * 4 + r) * 256 + c];
  }
}

__global__ __launch_bounds__(256) void zero_flags(float* __restrict__ ws) {
  int i = blockIdx.x * 256 + threadIdx.x;
  if (i < FLAGS_N) ((unsigned*)ws)[FLA_OFF + i] = 0u;
}

// ---------------------------------------------------------------------------
// R10 pipelined kernel: 64 blocks. [0,32)=stage A, [32,64)=stage C.
// ---------------------------------------------------------------------------
__global__ __launch_bounds__(1024, 4) void snn_pipe(
    const float* __restrict__ input, const float* __restrict__ w1g,
    const float* __restrict__ b1g, const float* __restrict__ b2g,
    const float* __restrict__ b3g, const float* __restrict__ tcbg,
    const float* __restrict__ recbg, const float* __restrict__ fc1bg,
    const float* __restrict__ fc2wg, const float* __restrict__ tswg,
    const float* __restrict__ maskg,
    const float* __restrict__ c1sg, const float* __restrict__ c2sg,
    const float* __restrict__ c3sg, const float* __restrict__ tcsg,
    const float* __restrict__ rsg, const float* __restrict__ fsg,
    float* __restrict__ ws, float* __restrict__ out)
{
  const int tid = threadIdx.x;
  const int wv  = tid >> 6;
  const int ln  = tid & 63;
  unsigned* p2g   = (unsigned*)ws + P2G_OFF;
  unsigned* flagA = (unsigned*)ws + FLA_OFF;

  const int b = blockIdx.x & 31;

  if (blockIdx.x < 32) {
    // ======================= STAGE A: conv1 + conv2 + pool ==================
    const half8v* w2h = (const half8v*)ws;
    __shared__ float xt[100];
    __shared__ __align__(16) unsigned short s1b[84 * 64];
    __shared__ unsigned short s2b[36 * 128];
    __shared__ float b2L[128];
    __shared__ unsigned char p2nb[1152];

    const int co = ln, pos0 = wv;
    float w1r[9];
    #pragma unroll
    for (int k = 0; k < 9; ++k) w1r[k] = w1g[co * 9 + k];
    const float b1r = b1g[co];
    float sp1[4], cur1[4], vol1[4];
    #pragma unroll
    for (int j = 0; j < 4; ++j) {
      int pos = pos0 + 16 * j;
      sp1[j]  = c1sg[((0 * 32 + b) * 64 + co) * 64 + pos];
      cur1[j] = c1sg[((1 * 32 + b) * 64 + co) * 64 + pos];
      vol1[j] = c1sg[((2 * 32 + b) * 64 + co) * 64 + pos];
    }
    const int grpB = (wv < 8);
    const int nt2 = grpB ? wv : (wv - 8);
    const int mtA = grpB ? 0 : 2;
    const int mtB = 1;
    const int oc2 = nt2 * 16 + (ln & 15);
    int pybA, pybB;
    {
      int pA = mtA * 16 + (ln & 15);
      int pB = mtB * 16 + (ln & 15);
      pybA = (pA < 36) ? ((pA / 6) * 8 + (pA % 6)) : 64;
      pybB = (pB / 6) * 8 + (pB % 6);
    }
    float cur2[2][4], vol2[2][4];
    #pragma unroll
    for (int m = 0; m < 2; ++m) {
      int mt = m ? mtB : mtA;
      bool use = (m == 0) || grpB;
      #pragma unroll
      for (int r = 0; r < 4; ++r) {
        int p = mt * 16 + ((ln >> 4) << 2) + r;
        if (use && p < 36) {
          cur2[m][r] = c2sg[((1 * 32 + b) * 128 + oc2) * 36 + p];
          vol2[m][r] = c2sg[((2 * 32 + b) * 128 + oc2) * 36 + p];
        } else { cur2[m][r] = 0.f; vol2[m][r] = 0.f; }
      }
    }
    if (tid < 128) b2L[tid] = b2g[tid];
    if (tid < 640) ((unsigned*)s1b)[64 * 32 + tid] = 0u;
    __syncthreads();

    for (int t = 0; t < 100; ++t) {
      if (tid < 100) xt[tid] = input[(b * 100 + tid) * 100 + t];
      __syncthreads();

      // conv1 + LIF1
      #pragma unroll
      for (int j = 0; j < 4; ++j) {
        int pos = pos0 + 16 * j;
        int y = pos >> 3, x = pos & 7;
        float psp = b1r;
        #pragma unroll
        for (int kk = 0; kk < 9; ++kk) {
          int ky = kk / 3, kx = kk - ky * 3;
          psp = fmaf(xt[(y + ky) * 10 + x + kx], w1r[kk], psp);
        }
        float cur = 0.5f * cur1[j] + psp;
        float vol = 0.75f * vol1[j] * (1.f - sp1[j]) + cur;
        float sp  = (vol > VTH) ? 1.f : 0.f;
        cur1[j] = cur; vol1[j] = vol; sp1[j] = sp;
        unsigned short bits = (vol > VTH) ? (unsigned short)0x3C00 : (unsigned short)0;
        int byte = ((pos << 7) + (co << 1)) ^ ((pos & 7) << 4);
        *(unsigned short*)((char*)s1b + byte) = bits;
      }
      __syncthreads();

      // conv2 MFMA (f16 scaled hi/lo split)
      {
        f32x4 acchA = {0,0,0,0}, acclA = {0,0,0,0};
        f32x4 acchB = {0,0,0,0}, acclB = {0,0,0,0};
        const int lnq16 = (ln >> 4) << 4;
        if (grpB) {
          #pragma unroll
          for (int kt = 0; kt < 18; ++kt) {
            const int tap = kt >> 1;
            const int dpos = (tap / 3) * 8 + (tap % 3);
            const int c0b = ((kt & 1) << 6) + lnq16;
            int posA = pybA + dpos, posB = pybB + dpos;
            int abA = ((posA << 7) + c0b) ^ ((posA & 7) << 4);
            int abB = ((posB << 7) + c0b) ^ ((posB & 7) << 4);
            half8v a0 = *(const half8v*)((const char*)s1b + abA);
            half8v a1 = *(const half8v*)((const char*)s1b + abB);
            half8v bh = w2h[(((kt << 3) + nt2) << 1) * 64 + ln];
            half8v bl = w2h[((((kt << 3) + nt2) << 1) + 1) * 64 + ln];
            acchA = __builtin_amdgcn_mfma_f32_16x16x32_f16(a0, bh, acchA, 0, 0, 0);
            acclA = __builtin_amdgcn_mfma_f32_16x16x32_f16(a0, bl, acclA, 0, 0, 0);
            acchB = __builtin_amdgcn_mfma_f32_16x16x32_f16(a1, bh, acchB, 0, 0, 0);
            acclB = __builtin_amdgcn_mfma_f32_16x16x32_f16(a1, bl, acclB, 0, 0, 0);
          }
        } else {
          #pragma unroll
          for (int kt = 0; kt < 18; ++kt) {
            const int tap = kt >> 1;
            const int dpos = (tap / 3) * 8 + (tap % 3);
            const int c0b = ((kt & 1) << 6) + lnq16;
            int posA = pybA + dpos;
            int abA = ((posA << 7) + c0b) ^ ((posA & 7) << 4);
            half8v a0 = *(const half8v*)((const char*)s1b + abA);
            half8v bh = w2h[(((kt << 3) + nt2) << 1) * 64 + ln];
            half8v bl = w2h[((((kt << 3) + nt2) << 1) + 1) * 64 + ln];
            acchA = __builtin_amdgcn_mfma_f32_16x16x32_f16(a0, bh, acchA, 0, 0, 0);
            acclA = __builtin_amdgcn_mfma_f32_16x16x32_f16(a0, bl, acclA, 0, 0, 0);
          }
        }
        float bias2 = b2L[oc2];
        #pragma unroll
        for (int m = 0; m < 2; ++m) {
          if (m == 1 && !grpB) break;
          int mt = m ? mtB : mtA;
          #pragma unroll
          for (int r = 0; r < 4; ++r) {
            int p = mt * 16 + ((ln >> 4) << 2) + r;
            if (p < 36) {
              float hi = m ? acchB[r] : acchA[r];
              float lo = m ? acclB[r] : acclA[r];
              float psp = hi + 0.000244140625f * lo + bias2;
              float spo = (vol2[m][r] > VTH) ? 1.f : 0.f;
              float cur = 0.5f * cur2[m][r] + psp;
              float vol = 0.75f * vol2[m][r] * (1.f - spo) + cur;
              cur2[m][r] = cur; vol2[m][r] = vol;
              s2b[p * 128 + oc2] = (vol > VTH) ? (unsigned short)0x3C00 : (unsigned short)0;
            }
          }
        }
      }
      __syncthreads();

      // pool: spike-count nibbles (pooled value = n * 0.25, exact)
      if (tid < 576) {
        int pp = tid >> 6, c0 = 2 * (tid & 63);
        int sy = (pp / 3) * 2, sx = (pp % 3) * 2;
        int n0 = (s2b[(sy * 6 + sx) * 128 + c0] != 0) + (s2b[(sy * 6 + sx + 1) * 128 + c0] != 0)
               + (s2b[((sy + 1) * 6 + sx) * 128 + c0] != 0) + (s2b[((sy + 1) * 6 + sx + 1) * 128 + c0] != 0);
        int c1 = c0 + 1;
        int n1 = (s2b[(sy * 6 + sx) * 128 + c1] != 0) + (s2b[(sy * 6 + sx + 1) * 128 + c1] != 0)
               + (s2b[((sy + 1) * 6 + sx) * 128 + c1] != 0) + (s2b[((sy + 1) * 6 + sx + 1) * 128 + c1] != 0);
        p2nb[pp * 128 + c0] = (unsigned char)n0;
        p2nb[pp * 128 + c1] = (unsigned char)n1;
      }
      __syncthreads();
      // publish nibbles via write-through relaxed atomics (no L2 dirty lines)
      if (tid < 144) {
        unsigned dwv = 0;
        #pragma unroll
        for (int j = 0; j < 8; ++j)
          dwv |= ((unsigned)p2nb[8 * tid + j] & 0xFu) << (4 * j);
        __hip_atomic_store(&p2g[(b * 100 + t) * 144 + tid], dwv,
                           __ATOMIC_RELAXED, __HIP_MEMORY_SCOPE_AGENT);
      }
      if ((t & 3) == 3) {
        asm volatile("s_waitcnt vmcnt(0)" ::: "memory");  // per-wave: WT stores acked at LLC
        __syncthreads();                                   // all waves drained
        if (tid == 0)
          __hip_atomic_store(&flagA[b * 25 + (t >> 2)], 1u,
                             __ATOMIC_RELAXED, __HIP_MEMORY_SCOPE_AGENT);
      }
    }
  } else {
    // ============ STAGE C: conv3(chunked) + tc + rec + fc1 + fc2 ============
    const float4* w3p  = (const float4*)(ws + W3P_OFF);
    const float4* tcp  = (const float4*)(ws + TCP_OFF);
    const float4* recp = (const float4*)(ws + RECP_OFF);
    const float4* fc1p = (const float4*)(ws + FC1P_OFF);

    __shared__ float p2L[4][1152];
    __shared__ float psp3[4][256];
    __shared__ __align__(16) float scratch[8192];   // 2 regions of 4096 floats
    __shared__ unsigned long long histB[12];        // [3 ring rows][4 chunks]
    __shared__ unsigned long long rspB[4];
    __shared__ float b3L[256], tcbL[768], recbL[256], fc1bL[128];
    __shared__ float fc2wL[256], maskL[128], tswL[100];
    __shared__ float accv[2];
    __shared__ float wpart[2][2];

    float c3sp = 0.f, c3cur = 0.f, c3vol = 0.f;
    float tcsp = 0.f, tccur = 0.f, tcvol = 0.f;
    float rspv = 0.f, rcur = 0.f, rvol = 0.f;
    float fsp = 0.f, fcur = 0.f, fvol = 0.f;
    if (tid < 256) {
      c3sp  = c3sg[(0 * 32 + b) * 256 + tid];
      c3cur = c3sg[(1 * 32 + b) * 256 + tid];
      c3vol = c3sg[(2 * 32 + b) * 256 + tid];
      tcsp  = tcsg[(0 * 32 + b) * 256 + tid];
      tccur = tcsg[(1 * 32 + b) * 256 + tid];
      tcvol = tcsg[(2 * 32 + b) * 256 + tid];
      rspv  = rsg[(0 * 32 + b) * 256 + tid];
      rcur  = rsg[(1 * 32 + b) * 256 + tid];
      rvol  = rsg[(2 * 32 + b) * 256 + tid];
      b3L[tid]   = b3g[tid];
      recbL[tid] = recbg[tid];
      tcbL[tid]       = tcbg[tid];
      tcbL[256 + tid] = tcbg[256 + tid];
      tcbL[512 + tid] = tcbg[512 + tid];
      unsigned long long bl = __ballot(rspv != 0.f);
      if (ln == 0) rspB[wv] = bl;
    }
    if (tid < 128) {
      fsp   = fsg[(0 * 32 + b) * 128 + tid];
      fcur  = fsg[(1 * 32 + b) * 128 + tid];
      fvol  = fsg[(2 * 32 + b) * 128 + tid];
      fc1bL[tid] = fc1bg[tid];
      maskL[tid] = maskg[b * 128 + tid];
      fc2wL[tid]       = fc2wg[tid];
      fc2wL[128 + tid] = fc2wg[128 + tid];
    }
    if (tid < 100) tswL[tid] = tswg[tid];
    if (tid < 12) histB[tid] = 0ull;
    if (tid == 0) { accv[0] = 0.f; accv[1] = 0.f; }
    __syncthreads();

    for (int t = 0; t < 100; ++t) {
      const int tm3 = t % 3;
      const int j4 = t & 3;
      const int bt = b * 100 + t;

      if (j4 == 0) {
        // ---- chunk head: wait flag, load 4 steps of p2, conv3 x4 ----
        if (tid == 0) {
          unsigned* f = &flagA[b * 25 + (t >> 2)];
          int guard = 0;
          while (__hip_atomic_load(f, __ATOMIC_RELAXED, __HIP_MEMORY_SCOPE_AGENT) == 0u) {
            __builtin_amdgcn_s_sleep(8);
            if (++guard > 4000000) break;
          }
        }
        __syncthreads();
        if (tid < 576) {
          #pragma unroll
          for (int s = 0; s < 4; ++s) {
            unsigned dwv = __hip_atomic_load(&p2g[(bt + s) * 144 + (tid >> 2)],
                                             __ATOMIC_RELAXED, __HIP_MEMORY_SCOPE_AGENT);
            int sh = (tid & 3) * 8;
            p2L[s][2 * tid]     = 0.25f * (float)((dwv >> sh) & 0xF);
            p2L[s][2 * tid + 1] = 0.25f * (float)((dwv >> (sh + 4)) & 0xF);
          }
        }
        __syncthreads();

        // conv3 dense stream, weights read once for 4 steps.
        float4 a0 = {0,0,0,0}, a1 = {0,0,0,0}, a2 = {0,0,0,0}, a3 = {0,0,0,0};
        {
          int base = wv * 72;
          #pragma unroll 8
          for (int i = 0; i < 72; ++i) {
            int k = base + i;
            float4 w = w3p[k * 64 + ln];
            float v0 = p2L[0][k], v1 = p2L[1][k], v2 = p2L[2][k], v3 = p2L[3][k];
            a0.x = fmaf(v0, w.x, a0.x); a0.y = fmaf(v0, w.y, a0.y);
            a0.z = fmaf(v0, w.z, a0.z); a0.w = fmaf(v0, w.w, a0.w);
            a1.x = fmaf(v1, w.x, a1.x); a1.y = fmaf(v1, w.y, a1.y);
            a1.z = fmaf(v1, w.z, a1.z); a1.w = fmaf(v1, w.w, a1.w);
            a2.x = fmaf(v2, w.x, a2.x); a2.y = fmaf(v2, w.y, a2.y);
            a2.z = fmaf(v2, w.z, a2.z); a2.w = fmaf(v2, w.w, a2.w);
            a3.x = fmaf(v3, w.x, a3.x); a3.y = fmaf(v3, w.y, a3.y);
            a3.z = fmaf(v3, w.z, a3.z); a3.w = fmaf(v3, w.w, a3.w);
          }
        }
        ((float4*)scratch)[wv * 64 + ln] = a0;
        ((float4*)(scratch + 4096))[wv * 64 + ln] = a1;
        __syncthreads();
        if (tid < 256) {
          float s0 = b3L[tid], s1 = b3L[tid];
          #pragma unroll
          for (int ks = 0; ks < 16; ++ks) {
            s0 += scratch[ks * 256 + tid];
            s1 += scratch[4096 + ks * 256 + tid];
          }
          psp3[0][tid] = s0; psp3[1][tid] = s1;
        }
        __syncthreads();
        ((float4*)scratch)[wv * 64 + ln] = a2;
        ((float4*)(scratch + 4096))[wv * 64 + ln] = a3;
        __syncthreads();
        if (tid < 256) {
          float s2 = b3L[tid], s3 = b3L[tid];
          #pragma unroll
          for (int ks = 0; ks < 16; ++ks) {
            s2 += scratch[ks * 256 + tid];
            s3 += scratch[4096 + ks * 256 + tid];
          }
          psp3[2][tid] = s2; psp3[3][tid] = s3;
        }
        __syncthreads();
      }

      // ---- per-step: LIF3 -> hist bits ----
      if (tid < 256) {
        float s = psp3[j4][tid];
        float cur = 0.5f * c3cur + s;
        float vol = 0.75f * c3vol * (1.f - c3sp) + cur;
        float sp  = (vol > VTH) ? 1.f : 0.f;
        c3cur = cur; c3vol = vol; c3sp = sp;
        unsigned long long bl = __ballot(sp != 0.f);
        if (ln == 0) histB[tm3 * 4 + wv] = bl;
      }
      __syncthreads();

      // ---- tc stream (waves 0-11) || rec stream (waves 12-15) ----
      if (wv < 12) {
        int kk = wv >> 2, g = wv & 3;
        int row = tm3 + 1 + kk; if (row >= 3) row -= 3;
        unsigned long long m = histB[row * 4 + g];
        float4 a = {0.f, 0.f, 0.f, 0.f};
        while (m) {
          int bit = __builtin_ctzll(m);
          m &= m - 1;
          int k = kk * 256 + g * 64 + bit;
          float4 w = tcp[k * 64 + ln];
          a.x += w.x; a.y += w.y; a.z += w.z; a.w += w.w;
        }
        ((float4*)scratch)[wv * 64 + ln] = a;
      } else {
        int g = wv - 12;
        unsigned long long m = rspB[g];
        float4 a = {0.f, 0.f, 0.f, 0.f};
        while (m) {
          int bit = __builtin_ctzll(m);
          m &= m - 1;
          int k = g * 64 + bit;
          float4 w = recp[k * 64 + ln];
          a.x += w.x; a.y += w.y; a.z += w.z; a.w += w.w;
        }
        ((float4*)scratch)[wv * 64 + ln] = a;
      }
      __syncthreads();

      // ---- LIF4 (tc) + LIF5 (rec) + s5 bits ----
      if (tid < 256) {
        float s = 0.f;
        #pragma unroll
        for (int w = 0; w < 12; ++w) s += scratch[w * 256 + tid];
        #pragma unroll
        for (int kk = 0; kk < 3; ++kk)
          if (t >= 2 - kk) s += tcbL[kk * 256 + tid];
        float cur4 = 0.5f * tccur + s;
        float vol4 = 0.75f * tcvol * (1.f - tcsp) + cur4;
        float sp4  = (vol4 > VTH) ? 1.f : 0.f;
        tccur = cur4; tcvol = vol4; tcsp = sp4;

        float r = sp4 + recbL[tid];
        #pragma unroll
        for (int g = 0; g < 4; ++g) r += scratch[(12 + g) * 256 + tid];
        float cur5 = 0.5f * rcur + r;
        float vol5 = 0.75f * rvol * (1.f - rspv) + cur5;
        float sp5  = (vol5 > VTH) ? 1.f : 0.f;
        rcur = cur5; rvol = vol5; rspv = sp5;
        unsigned long long bl = __ballot(sp5 != 0.f);
        if (ln == 0) rspB[wv] = bl;
      }
      __syncthreads();

      // ---- fc1 stream: 16 waves x 16-k segments, even/odd lane halves ----
      {
        unsigned mask = (unsigned)((rspB[wv >> 2] >> ((wv & 3) * 16)) & 0xFFFFull);
        int jj = ln >> 5, q = ln & 31;
        float4 a = {0.f, 0.f, 0.f, 0.f};
        unsigned mm = mask;
        int i = 0;
        while (mm) {
          int bit = __builtin_ctz(mm);
          mm &= mm - 1;
          if ((i & 1) == jj) {
            int k = wv * 16 + bit;
            float4 w = fc1p[k * 32 + q];
            a.x += w.x; a.y += w.y; a.z += w.z; a.w += w.w;
          }
          ++i;
        }
        ((float4*)scratch)[wv * 64 + ln] = a;
      }
      __syncthreads();

      // ---- fc1 reduce + dropout LIF6 + fc2 partial ----
      if (tid < 128) {
        float s = fc1bL[tid];
        #pragma unroll
        for (int w = 0; w < 16; ++w)
          s += scratch[w * 256 + tid] + scratch[w * 256 + 128 + tid];
        float cur = (0.5f * fcur + s) * maskL[tid];
        float vol = 0.75f * fvol * (1.f - fsp) + cur;
        float sp  = (vol > VTH) ? 1.f : 0.f;
        fcur = cur; fvol = vol; fsp = sp;
        float v0 = sp * fc2wL[tid];
        float v1 = sp * fc2wL[128 + tid];
        #pragma unroll
        for (int off = 32; off > 0; off >>= 1) {
          v0 += __shfl_down(v0, off);
          v1 += __shfl_down(v1, off);
        }
        if (ln == 0) { wpart[wv][0] = v0; wpart[wv][1] = v1; }
      }
      __syncthreads();
      if (tid == 0) {
        float wt = tswL[t];
        accv[0] += wt * (wpart[0][0] + wpart[1][0]);
        accv[1] += wt * (wpart[0][1] + wpart[1][1]);
      }
    }
    __syncthreads();
    if (tid < 2) out[b * 2 + tid] = accv[tid];
  }
}

// ---------------------------------------------------------------------------
// R7 monolithic fallback (used when ws_size < WS_NEED_BYTES)
// ---------------------------------------------------------------------------
__global__ __launch_bounds__(1024, 4) void snn_main(
    const float* __restrict__ input, const float* __restrict__ w1g,
    const float* __restrict__ b1g, const float* __restrict__ b2g,
    const float* __restrict__ b3g, const float* __restrict__ tcbg,
    const float* __restrict__ recbg, const float* __restrict__ fc1bg,
    const float* __restrict__ fc2wg, const float* __restrict__ tswg,
    const float* __restrict__ maskg,
    const float* __restrict__ c1sg, const float* __restrict__ c2sg,
    const float* __restrict__ c3sg, const float* __restrict__ tcsg,
    const float* __restrict__ rsg, const float* __restrict__ fsg,
    const float* __restrict__ ws, float* __restrict__ out)
{
  const half8v* w2h  = (const half8v*)ws;
  const float4* w3p  = (const float4*)(ws + W3P_OFF);
  const float4* tcp  = (const float4*)(ws + TCP_OFF);
  const float4* recp = (const float4*)(ws + RECP_OFF);
  const float4* fc1p = (const float4*)(ws + FC1P_OFF);

  const int b   = blockIdx.x;
  const int tid = threadIdx.x;
  const int wv  = tid >> 6;
  const int ln  = tid & 63;

  __shared__ __align__(16) float scratch[4096];
  __shared__ __align__(16) unsigned short s1b[84 * 64];
  __shared__ unsigned short s2b[36 * 128];
  __shared__ float p2f[1152];
  __shared__ float xt[100];
  __shared__ float histf[768];
  __shared__ float s4v[256];
  __shared__ float c3cur[256], c3vol[256], c3sp[256];
  __shared__ float tccur[256], tcvol[256], tcsp[256];
  __shared__ float rcur[256],  rvol[256],  rsp[256];
  __shared__ float fcur[128],  fvol[128],  fsp[128];
  __shared__ float b3L[256], tcbL[768], recbL[256], fc1bL[128];
  __shared__ float fc2wL[256], maskL[128], tswL[100], b2L[128];
  __shared__ float accv[2];
  __shared__ float wpart[2][2];

  const int co = ln, pos0 = wv;
  float w1r[9];
  #pragma unroll
  for (int k = 0; k < 9; ++k) w1r[k] = w1g[co * 9 + k];
  const float b1r = b1g[co];
  float sp1[4], cur1[4], vol1[4];
  #pragma unroll
  for (int j = 0; j < 4; ++j) {
    int pos = pos0 + 16 * j;
    sp1[j]  = c1sg[((0 * 32 + b) * 64 + co) * 64 + pos];
    cur1[j] = c1sg[((1 * 32 + b) * 64 + co) * 64 + pos];
    vol1[j] = c1sg[((2 * 32 + b) * 64 + co) * 64 + pos];
  }
  const int grpB = (wv < 8);
  const int nt2 = grpB ? wv : (wv - 8);
  const int mtA = grpB ? 0 : 2;
  const int mtB = 1;
  const int oc2 = nt2 * 16 + (ln & 15);
  int pybA, pybB;
  {
    int pA = mtA * 16 + (ln & 15);
    int pB = mtB * 16 + (ln & 15);
    pybA = (pA < 36) ? ((pA / 6) * 8 + (pA % 6)) : 64;
    pybB = (pB / 6) * 8 + (pB % 6);
  }
  float cur2[2][4], vol2[2][4];
  #pragma unroll
  for (int m = 0; m < 2; ++m) {
    int mt = m ? mtB : mtA;
    bool use = (m == 0) || grpB;
    #pragma unroll
    for (int r = 0; r < 4; ++r) {
      int p = mt * 16 + ((ln >> 4) << 2) + r;
      if (use && p < 36) {
        cur2[m][r] = c2sg[((1 * 32 + b) * 128 + oc2) * 36 + p];
        vol2[m][r] = c2sg[((2 * 32 + b) * 128 + oc2) * 36 + p];
      } else { cur2[m][r] = 0.f; vol2[m][r] = 0.f; }
    }
  }
  if (tid < 256) {
    c3sp[tid]  = c3sg[(0 * 32 + b) * 256 + tid];
    c3cur[tid] = c3sg[(1 * 32 + b) * 256 + tid];
    c3vol[tid] = c3sg[(2 * 32 + b) * 256 + tid];
    tcsp[tid]  = tcsg[(0 * 32 + b) * 256 + tid];
    tccur[tid] = tcsg[(1 * 32 + b) * 256 + tid];
    tcvol[tid] = tcsg[(2 * 32 + b) * 256 + tid];
    rsp[tid]   = rsg[(0 * 32 + b) * 256 + tid];
    rcur[tid]  = rsg[(1 * 32 + b) * 256 + tid];
    rvol[tid]  = rsg[(2 * 32 + b) * 256 + tid];
    b3L[tid]   = b3g[tid];
    recbL[tid] = recbg[tid];
    tcbL[tid]       = tcbg[tid];
    tcbL[256 + tid] = tcbg[256 + tid];
    tcbL[512 + tid] = tcbg[512 + tid];
    histf[tid] = 0.f; histf[256 + tid] = 0.f; histf[512 + tid] = 0.f;
  }
  if (tid < 128) {
    fsp[tid]   = fsg[(0 * 32 + b) * 128 + tid];
    fcur[tid]  = fsg[(1 * 32 + b) * 128 + tid];
    fvol[tid]  = fsg[(2 * 32 + b) * 128 + tid];
    fc1bL[tid] = fc1bg[tid];
    maskL[tid] = maskg[b * 128 + tid];
    b2L[tid]   = b2g[tid];
    fc2wL[tid]       = fc2wg[tid];
    fc2wL[128 + tid] = fc2wg[128 + tid];
  }
  if (tid < 100) tswL[tid] = tswg[tid];
  if (tid < 640) ((unsigned*)s1b)[64 * 32 + tid] = 0u;
  if (tid == 0) { accv[0] = 0.f; accv[1] = 0.f; }
  __syncthreads();

  for (int t = 0; t < 100; ++t) {
    const int tm3 = t % 3;
    if (tid < 100) xt[tid] = input[(b * 100 + tid) * 100 + t];
    __syncthreads();
    #pragma unroll
    for (int j = 0; j < 4; ++j) {
      int pos = pos0 + 16 * j;
      int y = pos >> 3, x = pos & 7;
      float psp = b1r;
      #pragma unroll
      for (int kk = 0; kk < 9; ++kk) {
        int ky = kk / 3, kx = kk - ky * 3;
        psp = fmaf(xt[(y + ky) * 10 + x + kx], w1r[kk], psp);
      }
      float cur = 0.5f * cur1[j] + psp;
      float vol = 0.75f * vol1[j] * (1.f - sp1[j]) + cur;
      float sp  = (vol > VTH) ? 1.f : 0.f;
      cur1[j] = cur; vol1[j] = vol; sp1[j] = sp;
      unsigned short bits = (vol > VTH) ? (unsigned short)0x3C00 : (unsigned short)0;
      int byte = ((pos << 7) + (co << 1)) ^ ((pos & 7) << 4);
      *(unsigned short*)((char*)s1b + byte) = bits;
    }
    __syncthreads();
    {
      f32x4 acchA = {0,0,0,0}, acclA = {0,0,0,0};
      f32x4 acchB = {0,0,0,0}, acclB = {0,0,0,0};
      const int lnq16 = (ln >> 4) << 4;
      if (grpB) {
        #pragma unroll
        for (int kt = 0; kt < 18; ++kt) {
          const int tap = kt >> 1;
          const int dpos = (tap / 3) * 8 + (tap % 3);
          const int c0b = ((kt & 1) << 6) + lnq16;
          int posA = pybA + dpos, posB = pybB + dpos;
          int abA = ((posA << 7) + c0b) ^ ((posA & 7) << 4);
          int abB = ((posB << 7) + c0b) ^ ((posB & 7) << 4);
          half8v a0 = *(const half8v*)((const char*)s1b + abA);
          half8v a1 = *(const half8v*)((const char*)s1b + abB);
          half8v bh = w2h[(((kt << 3) + nt2) << 1) * 64 + ln];
          half8v bl = w2h[((((kt << 3) + nt2) << 1) + 1) * 64 + ln];
          acchA = __builtin_amdgcn_mfma_f32_16x16x32_f16(a0, bh, acchA, 0, 0, 0);
          acclA = __builtin_amdgcn_mfma_f32_16x16x32_f16(a0, bl, acclA, 0, 0, 0);
          acchB = __builtin_amdgcn_mfma_f32_16x16x32_f16(a1, bh, acchB, 0, 0, 0);
          acclB = __builtin_amdgcn_mfma_f32_16x16x32_f16(a1, bl, acclB, 0, 0, 0);
        }
      } else {
        #pragma unroll
        for (int kt = 0; kt < 18; ++kt) {
          const int tap = kt >> 1;
          const int dpos = (tap / 3) * 8 + (tap % 3);
          const int c0b = ((kt & 1) << 6) + lnq16;
          int posA = pybA + dpos;
          int abA = ((posA << 7) + c0b) ^ ((posA & 7) << 4);
          half8v a0 = *(const half8v*)((const char*)s1b + abA);
          half8v bh = w2h[(((kt << 3) + nt2) << 1) * 64 + ln];
          half8v bl = w2h[((((kt << 3) + nt2) << 1) + 1) * 64 + ln];
          acchA = __builtin_amdgcn_mfma_f32_16x16x32_f16(a0, bh, acchA, 0, 0, 0);
          acclA = __builtin_amdgcn_mfma_f32_16x16x32_f16(a0, bl, acclA, 0, 0, 0);
        }
      }
      float bias2 = b2L[oc2];
      #pragma unroll
      for (int m = 0; m < 2; ++m) {
        if (m == 1 && !grpB) break;
        int mt = m ? mtB : mtA;
        #pragma unroll
        for (int r = 0; r < 4; ++r) {
          int p = mt * 16 + ((ln >> 4) << 2) + r;
          if (p < 36) {
            float hi = m ? acchB[r] : acchA[r];
            float lo = m ? acclB[r] : acclA[r];
            float psp = hi + 0.000244140625f * lo + bias2;
            float spo = (vol2[m][r] > VTH) ? 1.f : 0.f;
            float cur = 0.5f * cur2[m][r] + psp;
            float vol = 0.75f * vol2[m][r] * (1.f - spo) + cur;
            cur2[m][r] = cur; vol2[m][r] = vol;
            s2b[p * 128 + oc2] = (vol > VTH) ? (unsigned short)0x3C00 : (unsigned short)0;
          }
        }
      }
    }
    __syncthreads();
    {
      int c = tid & 127, pp = tid >> 7;
      int sy = (pp / 3) * 2, sx = (pp % 3) * 2;
      float v = h2f(s2b[(sy * 6 + sx) * 128 + c]) + h2f(s2b[(sy * 6 + sx + 1) * 128 + c])
              + h2f(s2b[((sy + 1) * 6 + sx) * 128 + c]) + h2f(s2b[((sy + 1) * 6 + sx + 1) * 128 + c]);
      p2f[pp * 128 + c] = 0.25f * v;
      if (tid < 128) {
        float v8 = h2f(s2b[(4 * 6 + 4) * 128 + c]) + h2f(s2b[(4 * 6 + 5) * 128 + c])
                 + h2f(s2b[(5 * 6 + 4) * 128 + c]) + h2f(s2b[(5 * 6 + 5) * 128 + c]);
        p2f[8 * 128 + c] = 0.25f * v8;
      }
    }
    __syncthreads();
    {
      int ocq = tid & 63, ks = tid >> 6;
      float4 a = {0.f, 0.f, 0.f, 0.f};
      const float4* wrow = w3p + (ks * 72) * 64 + ocq;
      const float* prow = p2f + ks * 72;
      #pragma unroll 8
      for (int i = 0; i < 72; ++i) {
        float pv = prow[i];
        if (pv != 0.f) {
          float4 w = wrow[i * 64];
          a.x = fmaf(pv, w.x, a.x); a.y = fmaf(pv, w.y, a.y);
          a.z = fmaf(pv, w.z, a.z); a.w = fmaf(pv, w.w, a.w);
        }
      }
      ((float4*)scratch)[tid] = a;
    }
    __syncthreads();
    if (tid < 256) {
      int d = tid;
      float s = b3L[d];
      #pragma unroll
      for (int ks = 0; ks < 16; ++ks) s += scratch[ks * 256 + d];
      float cur = 0.5f * c3cur[d] + s;
      float vol = 0.75f * c3vol[d] * (1.f - c3sp[d]) + cur;
      float sp  = (vol > VTH) ? 1.f : 0.f;
      c3cur[d] = cur; c3vol[d] = vol; c3sp[d] = sp;
      histf[tm3 * 256 + d] = sp;
    }
    __syncthreads();
    {
      int dq = tid & 63, ks = tid >> 6;
      float4 a = {0.f, 0.f, 0.f, 0.f};
      const float4* wrow = tcp + (ks * 48) * 64 + dq;
      #pragma unroll 8
      for (int i = 0; i < 48; ++i) {
        int k = ks * 48 + i;
        int kk = k >> 8;
        int vv = tm3 + 1 + kk; if (vv >= 3) vv -= 3;
        float hv = histf[(vv << 8) + (k & 255)];
        if (hv != 0.f) {
          float4 w = wrow[i * 64];
          a.x = fmaf(hv, w.x, a.x); a.y = fmaf(hv, w.y, a.y);
          a.z = fmaf(hv, w.z, a.z); a.w = fmaf(hv, w.w, a.w);
        }
      }
      ((float4*)scratch)[tid] = a;
    }
    __syncthreads();
    if (tid < 256) {
      int d = tid;
      float s = 0.f;
      #pragma unroll
      for (int ks = 0; ks < 16; ++ks) s += scratch[ks * 256 + d];
      #pragma unroll
      for (int kk = 0; kk < 3; ++kk)
        if (t >= 2 - kk) s += tcbL[kk * 256 + d];
      float cur = 0.5f * tccur[d] + s;
      float vol = 0.75f * tcvol[d] * (1.f - tcsp[d]) + cur;
      float sp  = (vol > VTH) ? 1.f : 0.f;
      tccur[d] = cur; tcvol[d] = vol; tcsp[d] = sp;
      s4v[d] = sp;
    }
    __syncthreads();
    {
      int dq = tid & 63, ks = tid >> 6;
      float4 a = {0.f, 0.f, 0.f, 0.f};
      const float4* wrow = recp + (ks * 16) * 64 + dq;
      const float* hr = rsp + ks * 16;
      #pragma unroll
      for (int i = 0; i < 16; ++i) {
        float hv = hr[i];
        if (hv != 0.f) {
          float4 w = wrow[i * 64];
          a.x = fmaf(hv, w.x, a.x); a.y = fmaf(hv, w.y, a.y);
          a.z = fmaf(hv, w.z, a.z); a.w = fmaf(hv, w.w, a.w);
        }
      }
      ((float4*)scratch)[tid] = a;
    }
    __syncthreads();
    if (tid < 256) {
      int d = tid;
      float s = s4v[d] + recbL[d];
      #pragma unroll
      for (int ks = 0; ks < 16; ++ks) s += scratch[ks * 256 + d];
      float cur = 0.5f * rcur[d] + s;
      float vol = 0.75f * rvol[d] * (1.f - rsp[d]) + cur;
      float sp  = (vol > VTH) ? 1.f : 0.f;
      rcur[d] = cur; rvol[d] = vol; rsp[d] = sp;
    }
    __syncthreads();
    {
      int dq = tid & 31, ks = tid >> 5;
      float4 a = {0.f, 0.f, 0.f, 0.f};
      const float4* wrow = fc1p + (ks * 8) * 32 + dq;
      const float* hr = rsp + ks * 8;
      #pragma unroll
      for (int i = 0; i < 8; ++i) {
        float hv = hr[i];
        if (hv != 0.f) {
          float4 w = wrow[i * 32];
          a.x = fmaf(hv, w.x, a.x); a.y = fmaf(hv, w.y, a.y);
          a.z = fmaf(hv, w.z, a.z); a.w = fmaf(hv, w.w, a.w);
        }
      }
      ((float4*)scratch)[tid] = a;
    }
    __syncthreads();
    if (tid < 128) {
      int d = tid;
      float s = fc1bL[d];
      #pragma unroll
      for (int ks = 0; ks < 32; ++ks) s += scratch[ks * 128 + d];
      float cur = (0.5f * fcur[d] + s) * maskL[d];
      float vol = 0.75f * fvol[d] * (1.f - fsp[d]) + cur;
      float sp  = (vol > VTH) ? 1.f : 0.f;
      fcur[d] = cur; fvol[d] = vol; fsp[d] = sp;
      float v0 = sp * fc2wL[d];
      float v1 = sp * fc2wL[128 + d];
      #pragma unroll
      for (int off = 32; off > 0; off >>= 1) {
        v0 += __shfl_down(v0, off);
        v1 += __shfl_down(v1, off);
      }
      if ((tid & 63) == 0) { wpart[tid >> 6][0] = v0; wpart[tid >> 6][1] = v1; }
    }
    __syncthreads();
    if (tid == 0) {
      float wt = tswL[t];
      accv[0] += wt * (wpart[0][0] + wpart[1][0]);
      accv[1] += wt * (wpart[0][1] + wpart[1][1]);
    }
  }
  __syncthreads();
  if (tid < 2) out[b * 2 + tid] = accv[tid];
}

extern "C" void kernel_launch(void* const* d_in, const int* in_sizes, int n_in,
                              void* d_out, int out_size, void* d_ws, size_t ws_size,
                              hipStream_t stream) {
  const float* input = (const float*)d_in[0];
  const float* w1    = (const float*)d_in[1];
  const float* b1    = (const float*)d_in[2];
  const float* w2    = (const float*)d_in[3];
  const float* b2    = (const float*)d_in[4];
  const float* w3    = (const float*)d_in[5];
  const float* b3    = (const float*)d_in[6];
  const float* tcw   = (const float*)d_in[7];
  const float* tcb   = (const float*)d_in[8];
  const float* recw  = (const float*)d_in[9];
  const float* recb  = (const float*)d_in[10];
  const float* fc1w  = (const float*)d_in[11];
  const float* fc1b  = (const float*)d_in[12];
  const float* fc2w  = (const float*)d_in[13];
  const float* tsw   = (const float*)d_in[14];
  const float* mask  = (const float*)d_in[15];
  const float* c1s   = (const float*)d_in[16];
  const float* c2s   = (const float*)d_in[17];
  const float* c3s   = (const float*)d_in[18];
  const float* tcs   = (const float*)d_in[19];
  const float* rs    = (const float*)d_in[20];
  const float* fs    = (const float*)d_in[21];
  float* ws   = (float*)d_ws;
  float* outp = (float*)d_out;

  prep_weights<<<WS_FLOATS / 256, 256, 0, stream>>>(w2, w3, tcw, recw, fc1w, ws);
  if (ws_size >= WS_NEED_BYTES) {
    zero_flags<<<(FLAGS_N + 255) / 256, 256, 0, stream>>>(ws);
    snn_pipe<<<64, 1024, 0, stream>>>(input, w1, b1, b2, b3, tcb, recb, fc1b,
                                      fc2w, tsw, mask, c1s, c2s, c3s, tcs, rs, fs,
                                      ws, outp);
  } else {
    snn_main<<<32, 1024, 0, stream>>>(input, w1, b1, b2, b3, tcb, recb, fc1b,
                                      fc2w, tsw, mask, c1s, c2s, c3s, tcs, rs, fs,
                                      ws, outp);
  }
}